// Round 5
// baseline (139.005 us; speedup 1.0000x reference)
//
#include <hip/hip_runtime.h>
#include <hip/hip_bf16.h>

// Sparsemax over rows: z [8192, 8192] f32, a = 1.0.
//
// Algorithm (no sort): tau in [z_max-1, z_max] analytically, so filter to the
// ~20 candidates > z_max-1, solve Michelot fixed-point on them in one wave,
// broadcast tau, write max(z-tau,0). Block-wide Michelot fallback if the
// candidate buffer overflows (pathological rows only).
//
// R5 change: persistent blocks (grid=2048, 4 rows/block) with software
// prefetch: load row r+1 into a second register set before solving row r, so
// solve+write overlap the next row's HBM loads and read/write traffic
// interleaves steadily instead of per-block bursts.

#define ROW_D 8192
#define BLOCK 512
#define VPT 16    // 16 * 512 = 8192
#define NWAVE 8   // BLOCK/64
#define CAP 1024  // candidate buffer (typical occupancy ~20)
#define RPB 4     // rows per block

typedef float f32x4 __attribute__((ext_vector_type(4)));

__device__ __forceinline__ void load_row(const float* __restrict__ zr, int t,
                                         float v[VPT]) {
    const f32x4* z4 = (const f32x4*)zr;
#pragma unroll
    for (int j = 0; j < VPT / 4; ++j) {
        f32x4 q = __builtin_nontemporal_load(&z4[j * BLOCK + t]);
        v[j * 4 + 0] = q.x;
        v[j * 4 + 1] = q.y;
        v[j * 4 + 2] = q.z;
        v[j * 4 + 3] = q.w;
    }
}

__global__ __launch_bounds__(BLOCK, 8) void sparsemax_kernel(
    const float* __restrict__ z, float* __restrict__ out) {
    const int t = threadIdx.x;
    const int lane = t & 63;
    const int wave = t >> 6;
    const size_t row0 = (size_t)blockIdx.x * RPB;

    __shared__ float s_a[NWAVE];
    __shared__ float s_b[NWAVE];
    __shared__ float s_cand[CAP];
    __shared__ int s_cnt;
    __shared__ float s_tau;

    float vc[VPT], vn[VPT];
    load_row(z + row0 * ROW_D, t, vc);

#pragma unroll 1
    for (int i = 0; i < RPB; ++i) {
        // ---- prefetch next row while we solve this one ----
        if (i + 1 < RPB) load_row(z + (row0 + i + 1) * ROW_D, t, vn);

        // ---- block max reduction ----
        float m = vc[0];
#pragma unroll
        for (int j = 1; j < VPT; ++j) m = fmaxf(m, vc[j]);
#pragma unroll
        for (int off = 1; off < 64; off <<= 1)
            m = fmaxf(m, __shfl_xor(m, off, 64));
        if (t == 0) s_cnt = 0;
        if (lane == 0) s_a[wave] = m;
        __syncthreads();  // barrier 1
        float rmax = s_a[0];
#pragma unroll
        for (int w = 1; w < NWAVE; ++w) rmax = fmaxf(rmax, s_a[w]);
        const float thr = rmax - 1.0f;  // tau >= thr provably

        // ---- collect candidates > thr ----
#pragma unroll
        for (int j = 0; j < VPT; ++j) {
            if (vc[j] > thr) {
                int idx = atomicAdd(&s_cnt, 1);
                if (idx < CAP) s_cand[idx] = vc[j];
            }
        }
        __syncthreads();  // barrier 2
        const int cnt = s_cnt;  // uniform across block

        float tau;
        if (cnt <= CAP) {
            // ---- wave 0 solves Michelot on the candidate set ----
            if (wave == 0) {
                float S = 0.f, K = 0.f;
                for (int c = lane; c < cnt; c += 64) {
                    S += s_cand[c];
                    K += 1.f;
                }
#pragma unroll
                for (int off = 1; off < 64; off <<= 1) {
                    S += __shfl_xor(S, off, 64);
                    K += __shfl_xor(K, off, 64);
                }
                float tl = (S - 1.f) / K;  // <= tau* (Michelot invariant)
                for (int it = 0; it < 64; ++it) {
                    float ps = 0.f, pc = 0.f;
                    for (int c = lane; c < cnt; c += 64) {
                        float x = s_cand[c];
                        if (x > tl) {
                            ps += x;
                            pc += 1.f;
                        }
                    }
#pragma unroll
                    for (int off = 1; off < 64; off <<= 1) {
                        ps += __shfl_xor(ps, off, 64);
                        pc += __shfl_xor(pc, off, 64);
                    }
                    float nt = (ps - 1.f) / pc;
                    if (nt == tl) break;  // uniform within wave
                    tl = nt;
                }
                if (lane == 0) s_tau = tl;
            }
            __syncthreads();  // barrier 3
            tau = s_tau;
        } else {
            // ---- fallback: full-block Michelot (pathological rows) ----
            float s = 0.f;
#pragma unroll
            for (int j = 0; j < VPT; ++j) s += vc[j];
#pragma unroll
            for (int off = 1; off < 64; off <<= 1) s += __shfl_xor(s, off, 64);
            if (lane == 0) s_a[wave] = s;
            __syncthreads();
            float S0 = 0.f;
#pragma unroll
            for (int w = 0; w < NWAVE; ++w) S0 += s_a[w];
            tau = (S0 - 1.0f) / (float)ROW_D;
            for (int it = 0; it < 64; ++it) {
                float ps = 0.f, pc = 0.f;
#pragma unroll
                for (int j = 0; j < VPT; ++j) {
                    bool in = vc[j] > tau;
                    ps += in ? vc[j] : 0.f;
                    pc += in ? 1.f : 0.f;
                }
#pragma unroll
                for (int off = 1; off < 64; off <<= 1) {
                    ps += __shfl_xor(ps, off, 64);
                    pc += __shfl_xor(pc, off, 64);
                }
                __syncthreads();
                if (lane == 0) {
                    s_a[wave] = ps;
                    s_b[wave] = pc;
                }
                __syncthreads();
                float S = 0.f, K = 0.f;
#pragma unroll
                for (int w = 0; w < NWAVE; ++w) {
                    S += s_a[w];
                    K += s_b[w];
                }
                float nt = (S - 1.0f) / K;
                if (nt == tau) break;
                tau = nt;
            }
            __syncthreads();  // keep barrier structure aligned before reuse
        }

        // ---- write w = max(z - tau, 0), nontemporal float4 ----
        f32x4* o4 = (f32x4*)(out + (row0 + i) * ROW_D);
#pragma unroll
        for (int j = 0; j < VPT / 4; ++j) {
            f32x4 q;
            q.x = fmaxf(vc[j * 4 + 0] - tau, 0.f);
            q.y = fmaxf(vc[j * 4 + 1] - tau, 0.f);
            q.z = fmaxf(vc[j * 4 + 2] - tau, 0.f);
            q.w = fmaxf(vc[j * 4 + 3] - tau, 0.f);
            __builtin_nontemporal_store(q, &o4[j * BLOCK + t]);
        }

        // ---- rotate prefetched row into place (static indexing) ----
        if (i + 1 < RPB) {
#pragma unroll
            for (int j = 0; j < VPT; ++j) vc[j] = vn[j];
        }
    }
}

extern "C" void kernel_launch(void* const* d_in, const int* in_sizes, int n_in,
                              void* d_out, int out_size, void* d_ws, size_t ws_size,
                              hipStream_t stream) {
    const float* z = (const float*)d_in[0];
    float* out = (float*)d_out;
    const int rows = out_size / ROW_D;  // 8192
    sparsemax_kernel<<<rows / RPB, BLOCK, 0, stream>>>(z, out);
}

// Round 6
// 111.223 us; speedup vs baseline: 1.2498x; 1.2498x over previous
//
#include <hip/hip_runtime.h>
#include <hip/hip_bf16.h>

// Sparsemax over rows: z [8192, 8192] f32, a = 1.0.
//
// R6 structure: output is ~99.8% zeros, so split into two single-direction
// streams instead of one mixed read/write stream:
//   Kernel A: zero-fill d_out (pure write burst, ~7 TB/s fill rate)
//   Kernel B: read z, per row: max-reduce -> filter candidates > max-1
//             (tau in [max-1, max] analytically) -> wave-0 Michelot on the
//             ~20 candidates -> scatter-write ONLY the nonzeros.
//             Dense-write fallback if candidate buffer overflows.
// z loads are cached (z is ~LLC-sized; may stay L3-resident across replays);
// out stores are nontemporal (no-allocate, keep L3 for z).

#define ROW_D 8192
#define BLOCK 512
#define VPT 16    // 16 * 512 = 8192
#define NWAVE 8   // BLOCK/64
#define CAP 1024  // candidate buffer (typical occupancy ~20)

typedef float f32x4 __attribute__((ext_vector_type(4)));

__global__ __launch_bounds__(256) void fill_zero_kernel(f32x4* __restrict__ out,
                                                        int n4) {
    f32x4 zero = {0.f, 0.f, 0.f, 0.f};
    int stride = gridDim.x * blockDim.x;
    for (int i = blockIdx.x * blockDim.x + threadIdx.x; i < n4; i += stride)
        __builtin_nontemporal_store(zero, &out[i]);
}

__global__ __launch_bounds__(BLOCK, 8) void sparsemax_kernel(
    const float* __restrict__ z, float* __restrict__ out) {
    const int row = blockIdx.x;
    const f32x4* z4 = (const f32x4*)(z + (size_t)row * ROW_D);
    float* outr = out + (size_t)row * ROW_D;
    const int t = threadIdx.x;
    const int lane = t & 63;
    const int wave = t >> 6;

    __shared__ float s_a[NWAVE];
    __shared__ float s_b[NWAVE];
    __shared__ float s_cand[CAP];
    __shared__ int s_cnt;
    __shared__ float s_tau;

    // ---- load row into registers, coalesced CACHED float4 ----
    float v[VPT];
#pragma unroll
    for (int j = 0; j < VPT / 4; ++j) {
        f32x4 q = z4[j * BLOCK + t];
        v[j * 4 + 0] = q.x;
        v[j * 4 + 1] = q.y;
        v[j * 4 + 2] = q.z;
        v[j * 4 + 3] = q.w;
    }

    // ---- block max reduction ----
    float m = v[0];
#pragma unroll
    for (int j = 1; j < VPT; ++j) m = fmaxf(m, v[j]);
#pragma unroll
    for (int off = 1; off < 64; off <<= 1) m = fmaxf(m, __shfl_xor(m, off, 64));
    if (t == 0) s_cnt = 0;
    if (lane == 0) s_a[wave] = m;
    __syncthreads();
    float rmax = s_a[0];
#pragma unroll
    for (int w = 1; w < NWAVE; ++w) rmax = fmaxf(rmax, s_a[w]);
    const float thr = rmax - 1.0f;  // tau >= thr provably

    // ---- collect candidates > thr (remember which of mine qualified) ----
    unsigned mask = 0;
#pragma unroll
    for (int j = 0; j < VPT; ++j) {
        if (v[j] > thr) {
            mask |= (1u << j);
            int idx = atomicAdd(&s_cnt, 1);
            if (idx < CAP) s_cand[idx] = v[j];
        }
    }
    __syncthreads();
    const int cnt = s_cnt;  // uniform across block

    if (cnt <= CAP) {
        // ---- wave 0 solves Michelot on the candidate set ----
        if (wave == 0) {
            float S = 0.f, K = 0.f;
            for (int c = lane; c < cnt; c += 64) {
                S += s_cand[c];
                K += 1.f;
            }
#pragma unroll
            for (int off = 1; off < 64; off <<= 1) {
                S += __shfl_xor(S, off, 64);
                K += __shfl_xor(K, off, 64);
            }
            float tl = (S - 1.f) / K;  // <= tau* (Michelot invariant)
            for (int it = 0; it < 64; ++it) {
                float ps = 0.f, pc = 0.f;
                for (int c = lane; c < cnt; c += 64) {
                    float x = s_cand[c];
                    if (x > tl) {
                        ps += x;
                        pc += 1.f;
                    }
                }
#pragma unroll
                for (int off = 1; off < 64; off <<= 1) {
                    ps += __shfl_xor(ps, off, 64);
                    pc += __shfl_xor(pc, off, 64);
                }
                float nt = (ps - 1.f) / pc;
                if (nt == tl) break;  // uniform within wave
                tl = nt;
            }
            if (lane == 0) s_tau = tl;
        }
        __syncthreads();
        const float tau = s_tau;

        // ---- scatter-write only the nonzeros ----
        unsigned mm = mask;
        while (mm) {
            int j = __builtin_ctz(mm);
            mm &= mm - 1;
            float w = v[j] - tau;
            if (w > 0.f) {
                // v[j] = row[((j>>2)*BLOCK + t)*4 + (j&3)]
                int pos = ((j >> 2) * BLOCK + t) * 4 + (j & 3);
                outr[pos] = w;
            }
        }
    } else {
        // ---- fallback: full-block Michelot + dense write ----
        float s = 0.f;
#pragma unroll
        for (int j = 0; j < VPT; ++j) s += v[j];
#pragma unroll
        for (int off = 1; off < 64; off <<= 1) s += __shfl_xor(s, off, 64);
        if (lane == 0) s_a[wave] = s;
        __syncthreads();
        float S0 = 0.f;
#pragma unroll
        for (int w = 0; w < NWAVE; ++w) S0 += s_a[w];
        float tau = (S0 - 1.0f) / (float)ROW_D;
        for (int it = 0; it < 64; ++it) {
            float ps = 0.f, pc = 0.f;
#pragma unroll
            for (int j = 0; j < VPT; ++j) {
                bool in = v[j] > tau;
                ps += in ? v[j] : 0.f;
                pc += in ? 1.f : 0.f;
            }
#pragma unroll
            for (int off = 1; off < 64; off <<= 1) {
                ps += __shfl_xor(ps, off, 64);
                pc += __shfl_xor(pc, off, 64);
            }
            __syncthreads();
            if (lane == 0) {
                s_a[wave] = ps;
                s_b[wave] = pc;
            }
            __syncthreads();
            float S = 0.f, K = 0.f;
#pragma unroll
            for (int w = 0; w < NWAVE; ++w) {
                S += s_a[w];
                K += s_b[w];
            }
            float nt = (S - 1.0f) / K;
            if (nt == tau) break;
            tau = nt;
        }
        f32x4* o4 = (f32x4*)outr;
#pragma unroll
        for (int j = 0; j < VPT / 4; ++j) {
            f32x4 q;
            q.x = fmaxf(v[j * 4 + 0] - tau, 0.f);
            q.y = fmaxf(v[j * 4 + 1] - tau, 0.f);
            q.z = fmaxf(v[j * 4 + 2] - tau, 0.f);
            q.w = fmaxf(v[j * 4 + 3] - tau, 0.f);
            __builtin_nontemporal_store(q, &o4[j * BLOCK + t]);
        }
    }
}

extern "C" void kernel_launch(void* const* d_in, const int* in_sizes, int n_in,
                              void* d_out, int out_size, void* d_ws, size_t ws_size,
                              hipStream_t stream) {
    const float* z = (const float*)d_in[0];
    float* out = (float*)d_out;
    const int rows = out_size / ROW_D;  // 8192
    const int n4 = out_size / 4;
    fill_zero_kernel<<<2048, 256, 0, stream>>>((f32x4*)out, n4);
    sparsemax_kernel<<<rows, BLOCK, 0, stream>>>(z, out);
}

// Round 7
// 97.993 us; speedup vs baseline: 1.4185x; 1.1350x over previous
//
#include <hip/hip_runtime.h>
#include <hip/hip_bf16.h>

// Sparsemax over rows: z [8192, 8192] f32, a = 1.0.
//
// Algorithm (no sort): tau in [z_max-1, z_max] analytically, so filter to the
// ~20 candidates > z_max-1, solve Michelot fixed-point on them in one wave,
// broadcast tau, write max(z-tau,0). Block-wide Michelot fallback if the
// candidate buffer overflows (pathological near-uniform rows).
//
// R7 = revert to the R4 structure (best: 98.0 us, 5.48 TB/s effective =
// 87% of the 6.29 TB/s copy ceiling, minimum 537 MB HBM traffic).
// R5 (register prefetch across rows) spilled; R6 (fill+sparse-scatter split)
// added a redundant 268 MB output pass. Single fused pass is optimal.

#define ROW_D 8192
#define BLOCK 512
#define VPT 16    // 16 * 512 = 8192
#define NWAVE 8   // BLOCK/64
#define CAP 1024  // candidate buffer (typical occupancy ~20)

typedef float f32x4 __attribute__((ext_vector_type(4)));

__global__ __launch_bounds__(BLOCK, 8) void sparsemax_kernel(
    const float* __restrict__ z, float* __restrict__ out) {
    const int row = blockIdx.x;
    const f32x4* z4 = (const f32x4*)(z + (size_t)row * ROW_D);
    f32x4* o4 = (f32x4*)(out + (size_t)row * ROW_D);
    const int t = threadIdx.x;
    const int lane = t & 63;
    const int wave = t >> 6;

    __shared__ float s_a[NWAVE];
    __shared__ float s_b[NWAVE];
    __shared__ float s_cand[CAP];
    __shared__ int s_cnt;
    __shared__ float s_tau;

    // ---- load row into registers, coalesced nontemporal float4 ----
    float v[VPT];
#pragma unroll
    for (int j = 0; j < VPT / 4; ++j) {
        f32x4 q = __builtin_nontemporal_load(&z4[j * BLOCK + t]);
        v[j * 4 + 0] = q.x;
        v[j * 4 + 1] = q.y;
        v[j * 4 + 2] = q.z;
        v[j * 4 + 3] = q.w;
    }

    // ---- block max reduction ----
    float m = v[0];
#pragma unroll
    for (int j = 1; j < VPT; ++j) m = fmaxf(m, v[j]);
#pragma unroll
    for (int off = 1; off < 64; off <<= 1) m = fmaxf(m, __shfl_xor(m, off, 64));
    if (t == 0) s_cnt = 0;
    if (lane == 0) s_a[wave] = m;
    __syncthreads();
    float rmax = s_a[0];
#pragma unroll
    for (int w = 1; w < NWAVE; ++w) rmax = fmaxf(rmax, s_a[w]);
    const float thr = rmax - 1.0f;  // tau >= thr provably

    // ---- collect candidates > thr ----
#pragma unroll
    for (int j = 0; j < VPT; ++j) {
        if (v[j] > thr) {
            int idx = atomicAdd(&s_cnt, 1);
            if (idx < CAP) s_cand[idx] = v[j];
        }
    }
    __syncthreads();
    const int cnt = s_cnt;  // uniform across block

    float tau;
    if (cnt <= CAP) {
        // ---- wave 0 solves Michelot on the candidate set ----
        if (wave == 0) {
            float S = 0.f, K = 0.f;
            for (int i = lane; i < cnt; i += 64) {
                S += s_cand[i];
                K += 1.f;
            }
#pragma unroll
            for (int off = 1; off < 64; off <<= 1) {
                S += __shfl_xor(S, off, 64);
                K += __shfl_xor(K, off, 64);
            }
            float tl = (S - 1.f) / K;  // <= tau* (Michelot invariant)
            for (int it = 0; it < 64; ++it) {
                float ps = 0.f, pc = 0.f;
                for (int i = lane; i < cnt; i += 64) {
                    float x = s_cand[i];
                    if (x > tl) {
                        ps += x;
                        pc += 1.f;
                    }
                }
#pragma unroll
                for (int off = 1; off < 64; off <<= 1) {
                    ps += __shfl_xor(ps, off, 64);
                    pc += __shfl_xor(pc, off, 64);
                }
                float nt = (ps - 1.f) / pc;
                if (nt == tl) break;  // uniform within wave
                tl = nt;
            }
            if (lane == 0) s_tau = tl;
        }
        __syncthreads();
        tau = s_tau;
    } else {
        // ---- fallback: full-block Michelot (pathological rows) ----
        float s = 0.f;
#pragma unroll
        for (int j = 0; j < VPT; ++j) s += v[j];
#pragma unroll
        for (int off = 1; off < 64; off <<= 1) s += __shfl_xor(s, off, 64);
        if (lane == 0) s_a[wave] = s;
        __syncthreads();
        float S0 = 0.f;
#pragma unroll
        for (int w = 0; w < NWAVE; ++w) S0 += s_a[w];
        tau = (S0 - 1.0f) / (float)ROW_D;
        for (int it = 0; it < 64; ++it) {
            float ps = 0.f, pc = 0.f;
#pragma unroll
            for (int j = 0; j < VPT; ++j) {
                bool in = v[j] > tau;
                ps += in ? v[j] : 0.f;
                pc += in ? 1.f : 0.f;
            }
#pragma unroll
            for (int off = 1; off < 64; off <<= 1) {
                ps += __shfl_xor(ps, off, 64);
                pc += __shfl_xor(pc, off, 64);
            }
            __syncthreads();
            if (lane == 0) {
                s_a[wave] = ps;
                s_b[wave] = pc;
            }
            __syncthreads();
            float S = 0.f, K = 0.f;
#pragma unroll
            for (int w = 0; w < NWAVE; ++w) {
                S += s_a[w];
                K += s_b[w];
            }
            float nt = (S - 1.0f) / K;
            if (nt == tau) break;
            tau = nt;
        }
    }

    // ---- write w = max(z - tau, 0), nontemporal float4 ----
#pragma unroll
    for (int j = 0; j < VPT / 4; ++j) {
        f32x4 q;
        q.x = fmaxf(v[j * 4 + 0] - tau, 0.f);
        q.y = fmaxf(v[j * 4 + 1] - tau, 0.f);
        q.z = fmaxf(v[j * 4 + 2] - tau, 0.f);
        q.w = fmaxf(v[j * 4 + 3] - tau, 0.f);
        __builtin_nontemporal_store(q, &o4[j * BLOCK + t]);
    }
}

extern "C" void kernel_launch(void* const* d_in, const int* in_sizes, int n_in,
                              void* d_out, int out_size, void* d_ws, size_t ws_size,
                              hipStream_t stream) {
    const float* z = (const float*)d_in[0];
    float* out = (float*)d_out;
    const int rows = out_size / ROW_D;  // 8192
    sparsemax_kernel<<<rows, BLOCK, 0, stream>>>(z, out);
}